// Round 5
// baseline (337.326 us; speedup 1.0000x reference)
//
#include <hip/hip_runtime.h>

#define B_ 4
#define N_ 1024
#define F_ 128
#define R_ 16
#define E_ 65536
#define BN_ 4096

// ---------------- fused CSR build: hist + scan + fill, one block per graph ----------------
__global__ __launch_bounds__(1024) void csr_build(
    const int* __restrict__ eis, const int* __restrict__ eit,
    int* __restrict__ offs, int* __restrict__ csr) {
  int g = blockIdx.x;
  const int* ei = g ? eit : eis;
  int* o = offs + g * (BN_ + 1);
  int* cs = csr + g * E_;
  int tid = threadIdx.x;
  __shared__ int cnt[BN_];     // 16 KB: counts -> cursors
  __shared__ int ssum[1024];   // 4 KB: block scan
  for (int i = tid; i < BN_; i += 1024) cnt[i] = 0;
  __syncthreads();
  for (int e = tid; e < E_; e += 1024) atomicAdd(&cnt[ei[E_ + e]], 1);
  __syncthreads();
  int base = tid * 4;
  int c0 = cnt[base], c1 = cnt[base + 1], c2 = cnt[base + 2], c3 = cnt[base + 3];
  ssum[tid] = c0 + c1 + c2 + c3;
  __syncthreads();
  for (int d = 1; d < 1024; d <<= 1) {
    int v = (tid >= d) ? ssum[tid - d] : 0;
    __syncthreads();
    ssum[tid] += v;
    __syncthreads();
  }
  int prev = (tid == 0) ? 0 : ssum[tid - 1];
  int o0 = prev, o1 = o0 + c0, o2 = o1 + c1, o3 = o2 + c2;
  o[base] = o0; o[base + 1] = o1; o[base + 2] = o2; o[base + 3] = o3;
  if (tid == 1023) o[BN_] = ssum[1023];
  cnt[base] = o0; cnt[base + 1] = o1; cnt[base + 2] = o2; cnt[base + 3] = o3;
  __syncthreads();
  for (int e = tid; e < E_; e += 1024) {
    int src = ei[e], dst = ei[E_ + e];
    int pos = atomicAdd(&cnt[dst], 1);
    cs[pos] = src;
  }
}

// ---------------- psi1 aggregation via gather, 4-way ILP ----------------
__global__ __launch_bounds__(256) void gather_f(
    const float* __restrict__ xs, const float* __restrict__ xt,
    const int* __restrict__ csr, const int* __restrict__ offs,
    float* __restrict__ aggs, float* __restrict__ aggt) {
  const float* x = blockIdx.y ? xt : xs;
  const int* cs = csr + blockIdx.y * E_;
  const int* of = offs + blockIdx.y * (BN_ + 1);
  float* agg = blockIdx.y ? aggt : aggs;
  int node = blockIdx.x * 2 + (threadIdx.x >> 7);
  int ch = threadIdx.x & 127;
  int j0 = of[node], j1 = of[node + 1];
  float a0 = 0.f, a1 = 0.f, a2 = 0.f, a3 = 0.f;
  int j = j0;
  for (; j + 3 < j1; j += 4) {
    int s0 = cs[j], s1 = cs[j + 1], s2 = cs[j + 2], s3 = cs[j + 3];
    a0 += x[(size_t)s0 * F_ + ch];
    a1 += x[(size_t)s1 * F_ + ch];
    a2 += x[(size_t)s2 * F_ + ch];
    a3 += x[(size_t)s3 * F_ + ch];
  }
  for (; j < j1; j++) a0 += x[(size_t)cs[j] * F_ + ch];
  agg[(size_t)node * F_ + ch] = (a0 + a1) + (a2 + a3);
}

// ------------- h = relu(x@Ws + agg@Wn + b), M=4096 N=128 K=128x2 -------------
__global__ __launch_bounds__(256) void psi1_gemm(
    const float* __restrict__ xs, const float* __restrict__ aggs,
    const float* __restrict__ xt, const float* __restrict__ aggt,
    const float* __restrict__ Ws, const float* __restrict__ Wn,
    const float* __restrict__ bias, float* __restrict__ hs, float* __restrict__ ht) {
  const float* x   = blockIdx.z ? xt   : xs;
  const float* agg = blockIdx.z ? aggt : aggs;
  float*       h   = blockIdx.z ? ht   : hs;
  int n0 = blockIdx.x * 64, m0 = blockIdx.y * 64;
  int tid = threadIdx.x, tx = tid & 15, ty = tid >> 4;
  __shared__ __align__(16) float sA[16][68];
  __shared__ __align__(16) float sB[16][68];
  float acc[4][4] = {};
  for (int phase = 0; phase < 2; phase++) {
    const float* A  = phase ? agg : x;
    const float* Bw = phase ? Wn  : Ws;
    for (int kb = 0; kb < F_; kb += 16) {
      int row = tid >> 2, k4 = (tid & 3) * 4;
      float4 va = *(const float4*)(A + (size_t)(m0 + row) * F_ + kb + k4);
      sA[k4 + 0][row] = va.x; sA[k4 + 1][row] = va.y;
      sA[k4 + 2][row] = va.z; sA[k4 + 3][row] = va.w;
      int k = tid >> 4, n4 = (tid & 15) * 4;
      *(float4*)&sB[k][n4] = *(const float4*)(Bw + (size_t)(kb + k) * F_ + n0 + n4);
      __syncthreads();
#pragma unroll
      for (int kk = 0; kk < 16; kk++) {
        float a[4], bb[4];
        *(float4*)a  = *(const float4*)&sA[kk][ty * 4];
        *(float4*)bb = *(const float4*)&sB[kk][tx * 4];
#pragma unroll
        for (int i = 0; i < 4; i++)
#pragma unroll
          for (int j = 0; j < 4; j++) acc[i][j] += a[i] * bb[j];
      }
      __syncthreads();
    }
  }
  float4 bv = *(const float4*)(bias + n0 + tx * 4);
  float bj[4] = {bv.x, bv.y, bv.z, bv.w};
#pragma unroll
  for (int i = 0; i < 4; i++) {
    int m = m0 + ty * 4 + i;
    float4 o;
    o.x = fmaxf(acc[i][0] + bj[0], 0.f); o.y = fmaxf(acc[i][1] + bj[1], 0.f);
    o.z = fmaxf(acc[i][2] + bj[2], 0.f); o.w = fmaxf(acc[i][3] + bj[3], 0.f);
    *(float4*)(h + (size_t)m * F_ + n0 + tx * 4) = o;
  }
}

// ---------- S_hat[b] = h_s[b] @ h_t[b]^T  (NT), 128x128 tile, 8x8 micro ----------
__global__ __launch_bounds__(256) void shat_gemm(
    const float* __restrict__ hs, const float* __restrict__ ht, float* __restrict__ S) {
  int b = blockIdx.z;
  int n0 = blockIdx.x * 128, m0 = blockIdx.y * 128;
  int tid = threadIdx.x, tx = tid & 15, ty = tid >> 4;
  __shared__ __align__(16) float sA[16][132];
  __shared__ __align__(16) float sB[16][132];
  float acc[8][8] = {};
  const float* Ag = hs + (size_t)(b * N_ + m0) * F_;
  const float* Bg = ht + (size_t)(b * N_ + n0) * F_;
  for (int kb = 0; kb < F_; kb += 16) {
#pragma unroll
    for (int l = 0; l < 2; l++) {
      int idx = tid + l * 256;
      int row = idx >> 2, k4 = (idx & 3) * 4;
      float4 va = *(const float4*)(Ag + (size_t)row * F_ + kb + k4);
      sA[k4 + 0][row] = va.x; sA[k4 + 1][row] = va.y;
      sA[k4 + 2][row] = va.z; sA[k4 + 3][row] = va.w;
      float4 vb = *(const float4*)(Bg + (size_t)row * F_ + kb + k4);
      sB[k4 + 0][row] = vb.x; sB[k4 + 1][row] = vb.y;
      sB[k4 + 2][row] = vb.z; sB[k4 + 3][row] = vb.w;
    }
    __syncthreads();
#pragma unroll
    for (int kk = 0; kk < 16; kk++) {
      float a[8], bb[8];
      *(float4*)&a[0]  = *(const float4*)&sA[kk][ty * 8];
      *(float4*)&a[4]  = *(const float4*)&sA[kk][ty * 8 + 4];
      *(float4*)&bb[0] = *(const float4*)&sB[kk][tx * 8];
      *(float4*)&bb[4] = *(const float4*)&sB[kk][tx * 8 + 4];
#pragma unroll
      for (int i = 0; i < 8; i++)
#pragma unroll
        for (int j = 0; j < 8; j++) acc[i][j] += a[i] * bb[j];
    }
    __syncthreads();
  }
#pragma unroll
  for (int i = 0; i < 8; i++) {
    size_t off = ((size_t)(b * N_ + m0 + ty * 8 + i)) * N_ + n0 + tx * 8;
    float4 o0 = {acc[i][0], acc[i][1], acc[i][2], acc[i][3]};
    float4 o1 = {acc[i][4], acc[i][5], acc[i][6], acc[i][7]};
    *(float4*)(S + off) = o0; *(float4*)(S + off + 4) = o1;
  }
}

// ---------------- row softmax over N=1024, one block per row ----------------
__global__ __launch_bounds__(256) void softmax_row(
    const float* __restrict__ in, float* __restrict__ out) {
  int row = blockIdx.x;
  float4 v = ((const float4*)(in + (size_t)row * N_))[threadIdx.x];
  float m = fmaxf(fmaxf(v.x, v.y), fmaxf(v.z, v.w));
#pragma unroll
  for (int o = 32; o > 0; o >>= 1) m = fmaxf(m, __shfl_down(m, o, 64));
  __shared__ float rmax[4], rsum[4];
  int wave = threadIdx.x >> 6, lane = threadIdx.x & 63;
  if (lane == 0) rmax[wave] = m;
  __syncthreads();
  m = fmaxf(fmaxf(rmax[0], rmax[1]), fmaxf(rmax[2], rmax[3]));
  float e0 = __expf(v.x - m), e1 = __expf(v.y - m);
  float e2 = __expf(v.z - m), e3 = __expf(v.w - m);
  float s = e0 + e1 + e2 + e3;
#pragma unroll
  for (int o = 32; o > 0; o >>= 1) s += __shfl_down(s, o, 64);
  if (lane == 0) rsum[wave] = s;
  __syncthreads();
  s = rsum[0] + rsum[1] + rsum[2] + rsum[3];
  float inv = 1.f / s;
  float4 o4 = {e0 * inv, e1 * inv, e2 * inv, e3 * inv};
  ((float4*)(out + (size_t)row * N_))[threadIdx.x] = o4;
}

// ---- r_t partial: part[b][c][t][r] = sum_{s in chunk c} S[b,s,t]*r_s[b,s,r] ----
// EXP variant reads raw Shat + row stats and applies softmax on the fly.
template <bool EXP>
__global__ __launch_bounds__(256) void rt_part_k(
    const float* __restrict__ S, const float2* __restrict__ stats,
    const float* __restrict__ rs, float* __restrict__ part) {
  int b = blockIdx.z, c = blockIdx.y, t0 = blockIdx.x * 256;
  int tid = threadIdx.x;
  int s0 = c * 32;
  __shared__ float rsh[32][16];
  __shared__ float sstat[64];
  if (tid < 128) {
    int srow = tid >> 2, c4 = (tid & 3) * 4;
    float4 v = *(const float4*)(rs + ((size_t)(b * N_ + s0 + srow)) * R_ + c4);
    rsh[srow][c4] = v.x; rsh[srow][c4 + 1] = v.y;
    rsh[srow][c4 + 2] = v.z; rsh[srow][c4 + 3] = v.w;
  } else if (EXP && tid < 192) {
    sstat[tid - 128] = ((const float*)(stats + b * N_ + s0))[tid - 128];
  }
  __syncthreads();
  float acc[16] = {};
  const float* Sp = S + ((size_t)(b * N_ + s0)) * N_ + t0 + tid;
#pragma unroll
  for (int s = 0; s < 32; s++) {
    float sv = Sp[(size_t)s * N_];
    if (EXP) sv = __expf(sv - sstat[2 * s]) * sstat[2 * s + 1];
#pragma unroll
    for (int r = 0; r < 16; r++) acc[r] += sv * rsh[s][r];
  }
  float* o = part + ((size_t)((b * 32 + c) * N_) + t0 + tid) * R_;
  *(float4*)(o + 0)  = *(float4*)&acc[0];
  *(float4*)(o + 4)  = *(float4*)&acc[4];
  *(float4*)(o + 8)  = *(float4*)&acc[8];
  *(float4*)(o + 12) = *(float4*)&acc[12];
}

// ---- r_t reduce over 32 chunks ----
__global__ __launch_bounds__(256) void rt_reduce(
    const float* __restrict__ part, float* __restrict__ rt) {
  int gid = blockIdx.x * 256 + threadIdx.x;   // 16384 float4 outputs
  int b = gid >> 12, tr = gid & 4095;
  const float* p = part + (size_t)b * (32 * N_ * R_) + (size_t)tr * 4;
  float4 acc = {0.f, 0.f, 0.f, 0.f};
#pragma unroll
  for (int c = 0; c < 32; c++) {
    float4 v = *(const float4*)(p + (size_t)c * (N_ * R_));
    acc.x += v.x; acc.y += v.y; acc.z += v.z; acc.w += v.w;
  }
  ((float4*)rt)[gid] = acc;
}

// ---- fused gather + psi2 + @Wm1: P = relu(v@W2s + (gather v)@W2n + b2) @ Wm1 ----
__global__ __launch_bounds__(256) void gpsi2p(
    const float* __restrict__ vs, const float* __restrict__ vt,
    const int* __restrict__ csr, const int* __restrict__ offs,
    const float* __restrict__ W2s, const float* __restrict__ W2n,
    const float* __restrict__ b2, const float* __restrict__ Wm1,
    float* __restrict__ Ps, float* __restrict__ Pt) {
  const float* v = blockIdx.y ? vt : vs;
  const int* cs = csr + blockIdx.y * E_;
  const int* of = offs + blockIdx.y * (BN_ + 1);
  float* P = blockIdx.y ? Pt : Ps;
  int col = threadIdx.x & 15, row = threadIdx.x >> 4;
  int node = blockIdx.x * 16 + row;
  int j0 = of[node], j1 = of[node + 1];
  float a0 = 0.f, a1 = 0.f, a2 = 0.f, a3 = 0.f;
  int j = j0;
  for (; j + 3 < j1; j += 4) {
    int s0 = cs[j], s1 = cs[j + 1], s2 = cs[j + 2], s3 = cs[j + 3];
    a0 += v[(size_t)s0 * R_ + col];
    a1 += v[(size_t)s1 * R_ + col];
    a2 += v[(size_t)s2 * R_ + col];
    a3 += v[(size_t)s3 * R_ + col];
  }
  for (; j < j1; j++) a0 += v[(size_t)cs[j] * R_ + col];
  __shared__ float sWs[16][16], sWn[16][16], sWm[16][17];
  __shared__ float sv[16][17], sa[16][17], so[16][17];
  sWs[row][col] = W2s[row * 16 + col];
  sWn[row][col] = W2n[row * 16 + col];
  sWm[row][col] = Wm1[row * 16 + col];
  sv[row][col] = v[(size_t)node * R_ + col];
  sa[row][col] = (a0 + a1) + (a2 + a3);
  __syncthreads();
  float o = b2[col];
#pragma unroll
  for (int k = 0; k < 16; k++) o += sv[row][k] * sWs[k][col] + sa[row][k] * sWn[k][col];
  so[row][col] = fmaxf(o, 0.f);
  __syncthreads();
  float p = 0;
#pragma unroll
  for (int k = 0; k < 16; k++) p += so[row][k] * sWm[k][col];
  P[(size_t)node * R_ + col] = p;
}

// ---- full-row update: Shat[b,s,t] += MLP(Ps[s]-Pt[t]); 4 rows/block, whole rows ----
// LAST=0: write updated Shat + row stats (max, 1/sumexp).
// LAST=1: don't write Shat; apply in-block softmax and write SL directly.
template <int LAST>
__global__ __launch_bounds__(256) void upd_row(
    float* __restrict__ Shat, const float* __restrict__ Ps, const float* __restrict__ Pt,
    const float* __restrict__ bm1, const float* __restrict__ Wm2,
    const float* __restrict__ bm2, float2* __restrict__ stats, float* __restrict__ SL) {
  int b = blockIdx.y, s0 = blockIdx.x * 4;
  int tid = threadIdx.x;
  __shared__ __align__(16) float pt[256][17];
  __shared__ float ps[4][16];
  __shared__ float sb[16], sw[16];
  __shared__ float wred[4][4];  // [wave][row]
  if (tid < 64) ps[tid >> 4][tid & 15] = Ps[((size_t)(b * N_ + s0 + (tid >> 4))) * R_ + (tid & 15)];
  if (tid < 16) { sb[tid] = bm1[tid]; sw[tid] = Wm2[tid]; }
  float bm2v = bm2[0];
  float vals[4][4];  // [tile][row]
  for (int tile = 0; tile < 4; tile++) {
    int t0 = tile * 256;
    __syncthreads();
    for (int i = tid; i < 1024; i += 256) {
      int tr = i >> 2, c = (i & 3) * 4;
      float4 v = *(const float4*)(Pt + ((size_t)(b * N_ + t0 + tr)) * R_ + c);
      pt[tr][c] = v.x; pt[tr][c + 1] = v.y; pt[tr][c + 2] = v.z; pt[tr][c + 3] = v.w;
    }
    __syncthreads();
    float ptl[16];
#pragma unroll
    for (int r = 0; r < 16; r++) ptl[r] = pt[tid][r];
#pragma unroll
    for (int si = 0; si < 4; si++) {
      size_t off = ((size_t)(b * N_ + s0 + si)) * N_ + t0 + tid;
      float sum = bm2v;
#pragma unroll
      for (int r = 0; r < 16; r++) sum += fmaxf(ps[si][r] - ptl[r] + sb[r], 0.f) * sw[r];
      float vv = Shat[off] + sum;
      vals[tile][si] = vv;
      if (!LAST) Shat[off] = vv;
    }
  }
  // --- row max reduce ---
  int wave = tid >> 6, lane = tid & 63;
  float M[4];
#pragma unroll
  for (int si = 0; si < 4; si++) {
    float mm = fmaxf(fmaxf(vals[0][si], vals[1][si]), fmaxf(vals[2][si], vals[3][si]));
#pragma unroll
    for (int o = 32; o > 0; o >>= 1) mm = fmaxf(mm, __shfl_down(mm, o, 64));
    if (lane == 0) wred[wave][si] = mm;
  }
  __syncthreads();
#pragma unroll
  for (int si = 0; si < 4; si++)
    M[si] = fmaxf(fmaxf(wred[0][si], wred[1][si]), fmaxf(wred[2][si], wred[3][si]));
  __syncthreads();
  // --- row expsum reduce ---
  float L[4];
#pragma unroll
  for (int si = 0; si < 4; si++) {
    float ls = __expf(vals[0][si] - M[si]) + __expf(vals[1][si] - M[si]) +
               __expf(vals[2][si] - M[si]) + __expf(vals[3][si] - M[si]);
#pragma unroll
    for (int o = 32; o > 0; o >>= 1) ls += __shfl_down(ls, o, 64);
    if (lane == 0) wred[wave][si] = ls;
  }
  __syncthreads();
#pragma unroll
  for (int si = 0; si < 4; si++)
    L[si] = (wred[0][si] + wred[1][si]) + (wred[2][si] + wred[3][si]);
  if (LAST) {
#pragma unroll
    for (int si = 0; si < 4; si++) {
      float inv = 1.f / L[si];
#pragma unroll
      for (int tile = 0; tile < 4; tile++) {
        size_t off = ((size_t)(b * N_ + s0 + si)) * N_ + tile * 256 + tid;
        SL[off] = __expf(vals[tile][si] - M[si]) * inv;
      }
    }
  } else {
    if (tid < 4) stats[b * N_ + s0 + tid] = make_float2(M[tid], 1.f / L[tid]);
  }
}

extern "C" void kernel_launch(void* const* d_in, const int* in_sizes, int n_in,
                              void* d_out, int out_size, void* d_ws, size_t ws_size,
                              hipStream_t stream) {
  const float* x_s = (const float*)d_in[0];
  const int*   ei_s = (const int*)d_in[1];
  const float* x_t = (const float*)d_in[2];
  const int*   ei_t = (const int*)d_in[3];
  const float* W1s = (const float*)d_in[4];
  const float* W1n = (const float*)d_in[5];
  const float* b1  = (const float*)d_in[6];
  const float* W2s = (const float*)d_in[7];
  const float* W2n = (const float*)d_in[8];
  const float* b2  = (const float*)d_in[9];
  const float* Wm1 = (const float*)d_in[10];
  const float* bm1 = (const float*)d_in[11];
  const float* Wm2 = (const float*)d_in[12];
  const float* bm2 = (const float*)d_in[13];
  const float* r_steps = (const float*)d_in[14];

  float* out = (float*)d_out;
  float* S0 = out;                         // [4,1024,1024]
  float* SL = out + (size_t)B_ * N_ * N_;  // [4,1024,1024]

  float* ws = (float*)d_ws;
  float* agg_s = ws;                       // 524288   (dead after psi1_gemm)
  float* agg_t = ws + 524288;              // 524288   (dead after psi1_gemm)
  float* h_s   = ws + 1048576;             // 524288   (dead after shat_gemm)
  float* h_t   = ws + 1572864;             // 524288   (dead after shat_gemm)
  float* part  = ws;                       // 2097152 floats = 8MB, reuses agg+h region
  float* Shat  = ws + 2097152;             // 4194304
  float* rtb   = ws + 6291456;             // 65536
  float2* stats = (float2*)(ws + 6356992); // 8192 floats (4096 float2)
  float* Ps    = ws + 6488064;             // 65536
  float* Pt    = ws + 6553600;             // 65536
  int* offs    = (int*)(ws + 6619136);     // 8194 (2 x 4097)
  int* csr     = (int*)(ws + 6627332);     // 131072

  // ---- CSR build: one fused kernel, no global memset ----
  csr_build<<<2, 1024, 0, stream>>>(ei_s, ei_t, offs, csr);

  // ---- psi1 on both graphs ----
  gather_f<<<dim3(BN_ / 2, 2), 256, 0, stream>>>(x_s, x_t, csr, offs, agg_s, agg_t);
  psi1_gemm<<<dim3(2, 64, 2), 256, 0, stream>>>(x_s, agg_s, x_t, agg_t, W1s, W1n, b1, h_s, h_t);

  // ---- S_hat and S_0 ----
  shat_gemm<<<dim3(8, 8, 4), 256, 0, stream>>>(h_s, h_t, Shat);
  softmax_row<<<B_ * N_, 256, 0, stream>>>(Shat, S0);

  // ---- step 0 ----
  const float* rs0 = r_steps;
  rt_part_k<false><<<dim3(4, 32, 4), 256, 0, stream>>>(S0, nullptr, rs0, part);
  rt_reduce<<<64, 256, 0, stream>>>(part, rtb);
  gpsi2p<<<dim3(256, 2), 256, 0, stream>>>(rs0, rtb, csr, offs, W2s, W2n, b2, Wm1, Ps, Pt);
  upd_row<0><<<dim3(256, 4), 256, 0, stream>>>(Shat, Ps, Pt, bm1, Wm2, bm2, stats, nullptr);

  // ---- step 1 (softmax fused into rt_part via stats; S_L written by upd_row) ----
  const float* rs1 = r_steps + (size_t)B_ * N_ * R_;
  rt_part_k<true><<<dim3(4, 32, 4), 256, 0, stream>>>(Shat, stats, rs1, part);
  rt_reduce<<<64, 256, 0, stream>>>(part, rtb);
  gpsi2p<<<dim3(256, 2), 256, 0, stream>>>(rs1, rtb, csr, offs, W2s, W2n, b2, Wm1, Ps, Pt);
  upd_row<1><<<dim3(256, 4), 256, 0, stream>>>(Shat, Ps, Pt, bm1, Wm2, bm2, nullptr, SL);
}

// Round 6
// 272.600 us; speedup vs baseline: 1.2374x; 1.2374x over previous
//
#include <hip/hip_runtime.h>

#define B_ 4
#define N_ 1024
#define F_ 128
#define R_ 16
#define E_ 65536
#define BN_ 4096

// ---------------- CSR build: histogram of dst (parallel, global atomics) ----------------
__global__ __launch_bounds__(256) void hist_k(
    const int* __restrict__ eis, const int* __restrict__ eit, int* __restrict__ counts) {
  const int* ei = blockIdx.y ? eit : eis;
  int* c = counts + blockIdx.y * BN_;
  int e = blockIdx.x * 256 + threadIdx.x;
  atomicAdd(c + ei[E_ + e], 1);
}

// ---------------- CSR build: exclusive scan (4096 = 256 threads x 16) ----------------
__global__ __launch_bounds__(256) void csr_scan(
    const int* __restrict__ counts, int* __restrict__ offs, int* __restrict__ cursor) {
  const int* c = counts + blockIdx.x * BN_;
  int* o = offs + blockIdx.x * (BN_ + 1);
  int* cur = cursor + blockIdx.x * BN_;
  int tid = threadIdx.x;
  int base = tid * 16;
  int local[16], sum = 0;
#pragma unroll
  for (int i = 0; i < 16; i++) { local[i] = sum; sum += c[base + i]; }
  __shared__ int csum[256];
  csum[tid] = sum;
  __syncthreads();
  for (int d = 1; d < 256; d <<= 1) {
    int v = (tid >= d) ? csum[tid - d] : 0;
    __syncthreads();
    csum[tid] += v;
    __syncthreads();
  }
  int prev = (tid == 0) ? 0 : csum[tid - 1];
#pragma unroll
  for (int i = 0; i < 16; i++) { int off = prev + local[i]; o[base + i] = off; cur[base + i] = off; }
  if (tid == 255) o[BN_] = csum[255];
}

// ---------------- CSR build: fill src lists ----------------
__global__ __launch_bounds__(256) void csr_fill(
    const int* __restrict__ eis, const int* __restrict__ eit,
    int* __restrict__ cursor, int* __restrict__ csr) {
  const int* ei = blockIdx.y ? eit : eis;
  int* cur = cursor + blockIdx.y * BN_;
  int* cs = csr + blockIdx.y * E_;
  int e = blockIdx.x * 256 + threadIdx.x;
  int src = ei[e], dst = ei[E_ + e];
  int pos = atomicAdd(cur + dst, 1);
  cs[pos] = src;
}

// ---------------- psi1 aggregation via gather, 4-way ILP ----------------
__global__ __launch_bounds__(256) void gather_f(
    const float* __restrict__ xs, const float* __restrict__ xt,
    const int* __restrict__ csr, const int* __restrict__ offs,
    float* __restrict__ aggs, float* __restrict__ aggt) {
  const float* x = blockIdx.y ? xt : xs;
  const int* cs = csr + blockIdx.y * E_;
  const int* of = offs + blockIdx.y * (BN_ + 1);
  float* agg = blockIdx.y ? aggt : aggs;
  int node = blockIdx.x * 2 + (threadIdx.x >> 7);
  int ch = threadIdx.x & 127;
  int j0 = of[node], j1 = of[node + 1];
  float a0 = 0.f, a1 = 0.f, a2 = 0.f, a3 = 0.f;
  int j = j0;
  for (; j + 3 < j1; j += 4) {
    int s0 = cs[j], s1 = cs[j + 1], s2 = cs[j + 2], s3 = cs[j + 3];
    a0 += x[(size_t)s0 * F_ + ch];
    a1 += x[(size_t)s1 * F_ + ch];
    a2 += x[(size_t)s2 * F_ + ch];
    a3 += x[(size_t)s3 * F_ + ch];
  }
  for (; j < j1; j++) a0 += x[(size_t)cs[j] * F_ + ch];
  agg[(size_t)node * F_ + ch] = (a0 + a1) + (a2 + a3);
}

// ------------- h = relu(x@Ws + agg@Wn + b), M=4096 N=128 K=128x2 -------------
__global__ __launch_bounds__(256) void psi1_gemm(
    const float* __restrict__ xs, const float* __restrict__ aggs,
    const float* __restrict__ xt, const float* __restrict__ aggt,
    const float* __restrict__ Ws, const float* __restrict__ Wn,
    const float* __restrict__ bias, float* __restrict__ hs, float* __restrict__ ht) {
  const float* x   = blockIdx.z ? xt   : xs;
  const float* agg = blockIdx.z ? aggt : aggs;
  float*       h   = blockIdx.z ? ht   : hs;
  int n0 = blockIdx.x * 64, m0 = blockIdx.y * 64;
  int tid = threadIdx.x, tx = tid & 15, ty = tid >> 4;
  __shared__ __align__(16) float sA[16][68];
  __shared__ __align__(16) float sB[16][68];
  float acc[4][4] = {};
  for (int phase = 0; phase < 2; phase++) {
    const float* A  = phase ? agg : x;
    const float* Bw = phase ? Wn  : Ws;
    for (int kb = 0; kb < F_; kb += 16) {
      int row = tid >> 2, k4 = (tid & 3) * 4;
      float4 va = *(const float4*)(A + (size_t)(m0 + row) * F_ + kb + k4);
      sA[k4 + 0][row] = va.x; sA[k4 + 1][row] = va.y;
      sA[k4 + 2][row] = va.z; sA[k4 + 3][row] = va.w;
      int k = tid >> 4, n4 = (tid & 15) * 4;
      *(float4*)&sB[k][n4] = *(const float4*)(Bw + (size_t)(kb + k) * F_ + n0 + n4);
      __syncthreads();
#pragma unroll
      for (int kk = 0; kk < 16; kk++) {
        float a[4], bb[4];
        *(float4*)a  = *(const float4*)&sA[kk][ty * 4];
        *(float4*)bb = *(const float4*)&sB[kk][tx * 4];
#pragma unroll
        for (int i = 0; i < 4; i++)
#pragma unroll
          for (int j = 0; j < 4; j++) acc[i][j] += a[i] * bb[j];
      }
      __syncthreads();
    }
  }
  float4 bv = *(const float4*)(bias + n0 + tx * 4);
  float bj[4] = {bv.x, bv.y, bv.z, bv.w};
#pragma unroll
  for (int i = 0; i < 4; i++) {
    int m = m0 + ty * 4 + i;
    float4 o;
    o.x = fmaxf(acc[i][0] + bj[0], 0.f); o.y = fmaxf(acc[i][1] + bj[1], 0.f);
    o.z = fmaxf(acc[i][2] + bj[2], 0.f); o.w = fmaxf(acc[i][3] + bj[3], 0.f);
    *(float4*)(h + (size_t)m * F_ + n0 + tx * 4) = o;
  }
}

// ---------- S_hat[b] = h_s[b] @ h_t[b]^T  (NT), 128x128 tile, 8x8 micro ----------
__global__ __launch_bounds__(256) void shat_gemm(
    const float* __restrict__ hs, const float* __restrict__ ht, float* __restrict__ S) {
  int b = blockIdx.z;
  int n0 = blockIdx.x * 128, m0 = blockIdx.y * 128;
  int tid = threadIdx.x, tx = tid & 15, ty = tid >> 4;
  __shared__ __align__(16) float sA[16][132];
  __shared__ __align__(16) float sB[16][132];
  float acc[8][8] = {};
  const float* Ag = hs + (size_t)(b * N_ + m0) * F_;
  const float* Bg = ht + (size_t)(b * N_ + n0) * F_;
  for (int kb = 0; kb < F_; kb += 16) {
#pragma unroll
    for (int l = 0; l < 2; l++) {
      int idx = tid + l * 256;
      int row = idx >> 2, k4 = (idx & 3) * 4;
      float4 va = *(const float4*)(Ag + (size_t)row * F_ + kb + k4);
      sA[k4 + 0][row] = va.x; sA[k4 + 1][row] = va.y;
      sA[k4 + 2][row] = va.z; sA[k4 + 3][row] = va.w;
      float4 vb = *(const float4*)(Bg + (size_t)row * F_ + kb + k4);
      sB[k4 + 0][row] = vb.x; sB[k4 + 1][row] = vb.y;
      sB[k4 + 2][row] = vb.z; sB[k4 + 3][row] = vb.w;
    }
    __syncthreads();
#pragma unroll
    for (int kk = 0; kk < 16; kk++) {
      float a[8], bb[8];
      *(float4*)&a[0]  = *(const float4*)&sA[kk][ty * 8];
      *(float4*)&a[4]  = *(const float4*)&sA[kk][ty * 8 + 4];
      *(float4*)&bb[0] = *(const float4*)&sB[kk][tx * 8];
      *(float4*)&bb[4] = *(const float4*)&sB[kk][tx * 8 + 4];
#pragma unroll
      for (int i = 0; i < 8; i++)
#pragma unroll
        for (int j = 0; j < 8; j++) acc[i][j] += a[i] * bb[j];
    }
    __syncthreads();
  }
#pragma unroll
  for (int i = 0; i < 8; i++) {
    size_t off = ((size_t)(b * N_ + m0 + ty * 8 + i)) * N_ + n0 + tx * 8;
    float4 o0 = {acc[i][0], acc[i][1], acc[i][2], acc[i][3]};
    float4 o1 = {acc[i][4], acc[i][5], acc[i][6], acc[i][7]};
    *(float4*)(S + off) = o0; *(float4*)(S + off + 4) = o1;
  }
}

// ---------------- row softmax over N=1024, one block per row ----------------
__global__ __launch_bounds__(256) void softmax_row(
    const float* __restrict__ in, float* __restrict__ out) {
  int row = blockIdx.x;
  float4 v = ((const float4*)(in + (size_t)row * N_))[threadIdx.x];
  float m = fmaxf(fmaxf(v.x, v.y), fmaxf(v.z, v.w));
#pragma unroll
  for (int o = 32; o > 0; o >>= 1) m = fmaxf(m, __shfl_down(m, o, 64));
  __shared__ float rmax[4], rsum[4];
  int wave = threadIdx.x >> 6, lane = threadIdx.x & 63;
  if (lane == 0) rmax[wave] = m;
  __syncthreads();
  m = fmaxf(fmaxf(rmax[0], rmax[1]), fmaxf(rmax[2], rmax[3]));
  float e0 = __expf(v.x - m), e1 = __expf(v.y - m);
  float e2 = __expf(v.z - m), e3 = __expf(v.w - m);
  float s = e0 + e1 + e2 + e3;
#pragma unroll
  for (int o = 32; o > 0; o >>= 1) s += __shfl_down(s, o, 64);
  if (lane == 0) rsum[wave] = s;
  __syncthreads();
  s = rsum[0] + rsum[1] + rsum[2] + rsum[3];
  float inv = 1.f / s;
  float4 o4 = {e0 * inv, e1 * inv, e2 * inv, e3 * inv};
  ((float4*)(out + (size_t)row * N_))[threadIdx.x] = o4;
}

// ---- r_t partial: part[b][c][t][r] = sum_{s in chunk c} S[b,s,t]*r_s[b,s,r] ----
// EXP variant reads raw Shat + row stats and applies softmax on the fly.
template <bool EXP>
__global__ __launch_bounds__(256) void rt_part_k(
    const float* __restrict__ S, const float2* __restrict__ stats,
    const float* __restrict__ rs, float* __restrict__ part) {
  int b = blockIdx.z, c = blockIdx.y, t0 = blockIdx.x * 256;
  int tid = threadIdx.x;
  int s0 = c * 32;
  __shared__ float rsh[32][16];
  __shared__ float sstat[64];
  if (tid < 128) {
    int srow = tid >> 2, c4 = (tid & 3) * 4;
    float4 v = *(const float4*)(rs + ((size_t)(b * N_ + s0 + srow)) * R_ + c4);
    rsh[srow][c4] = v.x; rsh[srow][c4 + 1] = v.y;
    rsh[srow][c4 + 2] = v.z; rsh[srow][c4 + 3] = v.w;
  } else if (EXP && tid < 192) {
    sstat[tid - 128] = ((const float*)(stats + b * N_ + s0))[tid - 128];
  }
  __syncthreads();
  float acc[16] = {};
  const float* Sp = S + ((size_t)(b * N_ + s0)) * N_ + t0 + tid;
#pragma unroll
  for (int s = 0; s < 32; s++) {
    float sv = Sp[(size_t)s * N_];
    if (EXP) sv = __expf(sv - sstat[2 * s]) * sstat[2 * s + 1];
#pragma unroll
    for (int r = 0; r < 16; r++) acc[r] += sv * rsh[s][r];
  }
  float* o = part + ((size_t)((b * 32 + c) * N_) + t0 + tid) * R_;
  *(float4*)(o + 0)  = *(float4*)&acc[0];
  *(float4*)(o + 4)  = *(float4*)&acc[4];
  *(float4*)(o + 8)  = *(float4*)&acc[8];
  *(float4*)(o + 12) = *(float4*)&acc[12];
}

// ---- r_t reduce over 32 chunks ----
__global__ __launch_bounds__(256) void rt_reduce(
    const float* __restrict__ part, float* __restrict__ rt) {
  int gid = blockIdx.x * 256 + threadIdx.x;   // 16384 float4 outputs
  int b = gid >> 12, tr = gid & 4095;
  const float* p = part + (size_t)b * (32 * N_ * R_) + (size_t)tr * 4;
  float4 acc = {0.f, 0.f, 0.f, 0.f};
#pragma unroll
  for (int c = 0; c < 32; c++) {
    float4 v = *(const float4*)(p + (size_t)c * (N_ * R_));
    acc.x += v.x; acc.y += v.y; acc.z += v.z; acc.w += v.w;
  }
  ((float4*)rt)[gid] = acc;
}

// ---- fused gather + psi2 + @Wm1: P = relu(v@W2s + (gather v)@W2n + b2) @ Wm1 ----
__global__ __launch_bounds__(256) void gpsi2p(
    const float* __restrict__ vs, const float* __restrict__ vt,
    const int* __restrict__ csr, const int* __restrict__ offs,
    const float* __restrict__ W2s, const float* __restrict__ W2n,
    const float* __restrict__ b2, const float* __restrict__ Wm1,
    float* __restrict__ Ps, float* __restrict__ Pt) {
  const float* v = blockIdx.y ? vt : vs;
  const int* cs = csr + blockIdx.y * E_;
  const int* of = offs + blockIdx.y * (BN_ + 1);
  float* P = blockIdx.y ? Pt : Ps;
  int col = threadIdx.x & 15, row = threadIdx.x >> 4;
  int node = blockIdx.x * 16 + row;
  int j0 = of[node], j1 = of[node + 1];
  float a0 = 0.f, a1 = 0.f, a2 = 0.f, a3 = 0.f;
  int j = j0;
  for (; j + 3 < j1; j += 4) {
    int s0 = cs[j], s1 = cs[j + 1], s2 = cs[j + 2], s3 = cs[j + 3];
    a0 += v[(size_t)s0 * R_ + col];
    a1 += v[(size_t)s1 * R_ + col];
    a2 += v[(size_t)s2 * R_ + col];
    a3 += v[(size_t)s3 * R_ + col];
  }
  for (; j < j1; j++) a0 += v[(size_t)cs[j] * R_ + col];
  __shared__ float sWs[16][16], sWn[16][16], sWm[16][17];
  __shared__ float sv[16][17], sa[16][17], so[16][17];
  sWs[row][col] = W2s[row * 16 + col];
  sWn[row][col] = W2n[row * 16 + col];
  sWm[row][col] = Wm1[row * 16 + col];
  sv[row][col] = v[(size_t)node * R_ + col];
  sa[row][col] = (a0 + a1) + (a2 + a3);
  __syncthreads();
  float o = b2[col];
#pragma unroll
  for (int k = 0; k < 16; k++) o += sv[row][k] * sWs[k][col] + sa[row][k] * sWn[k][col];
  so[row][col] = fmaxf(o, 0.f);
  __syncthreads();
  float p = 0;
#pragma unroll
  for (int k = 0; k < 16; k++) p += so[row][k] * sWm[k][col];
  P[(size_t)node * R_ + col] = p;
}

// ---- full-row update: Shat[b,s,t] += MLP(Ps[s]-Pt[t]); 4 rows/block, whole rows ----
// LAST=0: write updated Shat + row stats (max, 1/sumexp).
// LAST=1: don't write Shat; apply in-block softmax and write SL directly.
template <int LAST>
__global__ __launch_bounds__(256) void upd_row(
    float* __restrict__ Shat, const float* __restrict__ Ps, const float* __restrict__ Pt,
    const float* __restrict__ bm1, const float* __restrict__ Wm2,
    const float* __restrict__ bm2, float2* __restrict__ stats, float* __restrict__ SL) {
  int b = blockIdx.y, s0 = blockIdx.x * 4;
  int tid = threadIdx.x;
  __shared__ __align__(16) float pt[256][17];
  __shared__ float ps[4][16];
  __shared__ float sb[16], sw[16];
  __shared__ float wred[4][4];  // [wave][row]
  if (tid < 64) ps[tid >> 4][tid & 15] = Ps[((size_t)(b * N_ + s0 + (tid >> 4))) * R_ + (tid & 15)];
  if (tid < 16) { sb[tid] = bm1[tid]; sw[tid] = Wm2[tid]; }
  float bm2v = bm2[0];
  float vals[4][4];  // [tile][row]
  for (int tile = 0; tile < 4; tile++) {
    int t0 = tile * 256;
    __syncthreads();
    for (int i = tid; i < 1024; i += 256) {
      int tr = i >> 2, c = (i & 3) * 4;
      float4 v = *(const float4*)(Pt + ((size_t)(b * N_ + t0 + tr)) * R_ + c);
      pt[tr][c] = v.x; pt[tr][c + 1] = v.y; pt[tr][c + 2] = v.z; pt[tr][c + 3] = v.w;
    }
    __syncthreads();
    float ptl[16];
#pragma unroll
    for (int r = 0; r < 16; r++) ptl[r] = pt[tid][r];
#pragma unroll
    for (int si = 0; si < 4; si++) {
      size_t off = ((size_t)(b * N_ + s0 + si)) * N_ + t0 + tid;
      float sum = bm2v;
#pragma unroll
      for (int r = 0; r < 16; r++) sum += fmaxf(ps[si][r] - ptl[r] + sb[r], 0.f) * sw[r];
      float vv = Shat[off] + sum;
      vals[tile][si] = vv;
      if (!LAST) Shat[off] = vv;
    }
  }
  // --- row max reduce ---
  int wave = tid >> 6, lane = tid & 63;
  float M[4];
#pragma unroll
  for (int si = 0; si < 4; si++) {
    float mm = fmaxf(fmaxf(vals[0][si], vals[1][si]), fmaxf(vals[2][si], vals[3][si]));
#pragma unroll
    for (int o = 32; o > 0; o >>= 1) mm = fmaxf(mm, __shfl_down(mm, o, 64));
    if (lane == 0) wred[wave][si] = mm;
  }
  __syncthreads();
#pragma unroll
  for (int si = 0; si < 4; si++)
    M[si] = fmaxf(fmaxf(wred[0][si], wred[1][si]), fmaxf(wred[2][si], wred[3][si]));
  __syncthreads();
  // --- row expsum reduce ---
  float L[4];
#pragma unroll
  for (int si = 0; si < 4; si++) {
    float ls = __expf(vals[0][si] - M[si]) + __expf(vals[1][si] - M[si]) +
               __expf(vals[2][si] - M[si]) + __expf(vals[3][si] - M[si]);
#pragma unroll
    for (int o = 32; o > 0; o >>= 1) ls += __shfl_down(ls, o, 64);
    if (lane == 0) wred[wave][si] = ls;
  }
  __syncthreads();
#pragma unroll
  for (int si = 0; si < 4; si++)
    L[si] = (wred[0][si] + wred[1][si]) + (wred[2][si] + wred[3][si]);
  if (LAST) {
#pragma unroll
    for (int si = 0; si < 4; si++) {
      float inv = 1.f / L[si];
#pragma unroll
      for (int tile = 0; tile < 4; tile++) {
        size_t off = ((size_t)(b * N_ + s0 + si)) * N_ + tile * 256 + tid;
        SL[off] = __expf(vals[tile][si] - M[si]) * inv;
      }
    }
  } else {
    if (tid < 4) stats[b * N_ + s0 + tid] = make_float2(M[tid], 1.f / L[tid]);
  }
}

extern "C" void kernel_launch(void* const* d_in, const int* in_sizes, int n_in,
                              void* d_out, int out_size, void* d_ws, size_t ws_size,
                              hipStream_t stream) {
  const float* x_s = (const float*)d_in[0];
  const int*   ei_s = (const int*)d_in[1];
  const float* x_t = (const float*)d_in[2];
  const int*   ei_t = (const int*)d_in[3];
  const float* W1s = (const float*)d_in[4];
  const float* W1n = (const float*)d_in[5];
  const float* b1  = (const float*)d_in[6];
  const float* W2s = (const float*)d_in[7];
  const float* W2n = (const float*)d_in[8];
  const float* b2  = (const float*)d_in[9];
  const float* Wm1 = (const float*)d_in[10];
  const float* bm1 = (const float*)d_in[11];
  const float* Wm2 = (const float*)d_in[12];
  const float* bm2 = (const float*)d_in[13];
  const float* r_steps = (const float*)d_in[14];

  float* out = (float*)d_out;
  float* S0 = out;                         // [4,1024,1024]
  float* SL = out + (size_t)B_ * N_ * N_;  // [4,1024,1024]

  float* ws = (float*)d_ws;
  float* agg_s = ws;                       // 524288   (dead after psi1_gemm)
  float* agg_t = ws + 524288;              // 524288   (dead after psi1_gemm)
  float* h_s   = ws + 1048576;             // 524288   (dead after shat_gemm)
  float* h_t   = ws + 1572864;             // 524288   (dead after shat_gemm)
  float* part  = ws;                       // 2097152 floats = 8MB, reuses agg+h region
  float* Shat  = ws + 2097152;             // 4194304
  float* rtb   = ws + 6291456;             // 65536
  float2* stats = (float2*)(ws + 6356992); // 8192 floats (4096 float2)
  float* Ps    = ws + 6488064;             // 65536
  float* Pt    = ws + 6553600;             // 65536
  int* counts  = (int*)(ws + 6619136);     // 8192
  int* cursor  = (int*)(ws + 6627328);     // 8192
  int* offs    = (int*)(ws + 6635520);     // 8194 (2 x 4097)
  int* csr     = (int*)(ws + 6643720);     // 131072

  // ---- CSR build: parallel 4-dispatch chain (csr_build-in-1-block regressed: occ 0.3%) ----
  hipMemsetAsync(counts, 0, 2 * BN_ * sizeof(int), stream);
  hist_k<<<dim3(E_ / 256, 2), 256, 0, stream>>>(ei_s, ei_t, counts);
  csr_scan<<<2, 256, 0, stream>>>(counts, offs, cursor);
  csr_fill<<<dim3(E_ / 256, 2), 256, 0, stream>>>(ei_s, ei_t, cursor, csr);

  // ---- psi1 on both graphs ----
  gather_f<<<dim3(BN_ / 2, 2), 256, 0, stream>>>(x_s, x_t, csr, offs, agg_s, agg_t);
  psi1_gemm<<<dim3(2, 64, 2), 256, 0, stream>>>(x_s, agg_s, x_t, agg_t, W1s, W1n, b1, h_s, h_t);

  // ---- S_hat and S_0 ----
  shat_gemm<<<dim3(8, 8, 4), 256, 0, stream>>>(h_s, h_t, Shat);
  softmax_row<<<B_ * N_, 256, 0, stream>>>(Shat, S0);

  // ---- step 0 ----
  const float* rs0 = r_steps;
  rt_part_k<false><<<dim3(4, 32, 4), 256, 0, stream>>>(S0, nullptr, rs0, part);
  rt_reduce<<<64, 256, 0, stream>>>(part, rtb);
  gpsi2p<<<dim3(256, 2), 256, 0, stream>>>(rs0, rtb, csr, offs, W2s, W2n, b2, Wm1, Ps, Pt);
  upd_row<0><<<dim3(256, 4), 256, 0, stream>>>(Shat, Ps, Pt, bm1, Wm2, bm2, stats, nullptr);

  // ---- step 1 (softmax fused into rt_part via stats; S_L written by upd_row) ----
  const float* rs1 = r_steps + (size_t)B_ * N_ * R_;
  rt_part_k<true><<<dim3(4, 32, 4), 256, 0, stream>>>(Shat, stats, rs1, part);
  rt_reduce<<<64, 256, 0, stream>>>(part, rtb);
  gpsi2p<<<dim3(256, 2), 256, 0, stream>>>(rs1, rtb, csr, offs, W2s, W2n, b2, Wm1, Ps, Pt);
  upd_row<1><<<dim3(256, 4), 256, 0, stream>>>(Shat, Ps, Pt, bm1, Wm2, bm2, nullptr, SL);
}

// Round 7
// 256.751 us; speedup vs baseline: 1.3138x; 1.0617x over previous
//
#include <hip/hip_runtime.h>

#define B_ 4
#define N_ 1024
#define F_ 128
#define R_ 16
#define E_ 65536
#define BN_ 4096

// ---------------- CSR build: histogram of dst (parallel, global atomics) ----------------
__global__ __launch_bounds__(256) void hist_k(
    const int* __restrict__ eis, const int* __restrict__ eit, int* __restrict__ counts) {
  const int* ei = blockIdx.y ? eit : eis;
  int* c = counts + blockIdx.y * BN_;
  int e = blockIdx.x * 256 + threadIdx.x;
  atomicAdd(c + ei[E_ + e], 1);
}

// ---------------- CSR build: exclusive scan (4096 = 256 threads x 16) ----------------
__global__ __launch_bounds__(256) void csr_scan(
    const int* __restrict__ counts, int* __restrict__ offs, int* __restrict__ cursor) {
  const int* c = counts + blockIdx.x * BN_;
  int* o = offs + blockIdx.x * (BN_ + 1);
  int* cur = cursor + blockIdx.x * BN_;
  int tid = threadIdx.x;
  int base = tid * 16;
  int local[16], sum = 0;
#pragma unroll
  for (int i = 0; i < 16; i++) { local[i] = sum; sum += c[base + i]; }
  __shared__ int csum[256];
  csum[tid] = sum;
  __syncthreads();
  for (int d = 1; d < 256; d <<= 1) {
    int v = (tid >= d) ? csum[tid - d] : 0;
    __syncthreads();
    csum[tid] += v;
    __syncthreads();
  }
  int prev = (tid == 0) ? 0 : csum[tid - 1];
#pragma unroll
  for (int i = 0; i < 16; i++) { int off = prev + local[i]; o[base + i] = off; cur[base + i] = off; }
  if (tid == 255) o[BN_] = csum[255];
}

// ---------------- CSR build: fill src lists ----------------
__global__ __launch_bounds__(256) void csr_fill(
    const int* __restrict__ eis, const int* __restrict__ eit,
    int* __restrict__ cursor, int* __restrict__ csr) {
  const int* ei = blockIdx.y ? eit : eis;
  int* cur = cursor + blockIdx.y * BN_;
  int* cs = csr + blockIdx.y * E_;
  int e = blockIdx.x * 256 + threadIdx.x;
  int src = ei[e], dst = ei[E_ + e];
  int pos = atomicAdd(cur + dst, 1);
  cs[pos] = src;
}

// ---------------- psi1 aggregation via gather, 4-way ILP ----------------
__global__ __launch_bounds__(256) void gather_f(
    const float* __restrict__ xs, const float* __restrict__ xt,
    const int* __restrict__ csr, const int* __restrict__ offs,
    float* __restrict__ aggs, float* __restrict__ aggt) {
  const float* x = blockIdx.y ? xt : xs;
  const int* cs = csr + blockIdx.y * E_;
  const int* of = offs + blockIdx.y * (BN_ + 1);
  float* agg = blockIdx.y ? aggt : aggs;
  int node = blockIdx.x * 2 + (threadIdx.x >> 7);
  int ch = threadIdx.x & 127;
  int j0 = of[node], j1 = of[node + 1];
  float a0 = 0.f, a1 = 0.f, a2 = 0.f, a3 = 0.f;
  int j = j0;
  for (; j + 3 < j1; j += 4) {
    int s0 = cs[j], s1 = cs[j + 1], s2 = cs[j + 2], s3 = cs[j + 3];
    a0 += x[(size_t)s0 * F_ + ch];
    a1 += x[(size_t)s1 * F_ + ch];
    a2 += x[(size_t)s2 * F_ + ch];
    a3 += x[(size_t)s3 * F_ + ch];
  }
  for (; j < j1; j++) a0 += x[(size_t)cs[j] * F_ + ch];
  agg[(size_t)node * F_ + ch] = (a0 + a1) + (a2 + a3);
}

// ------------- h = relu(x@Ws + agg@Wn + b), M=4096 N=128 K=128x2 -------------
__global__ __launch_bounds__(256) void psi1_gemm(
    const float* __restrict__ xs, const float* __restrict__ aggs,
    const float* __restrict__ xt, const float* __restrict__ aggt,
    const float* __restrict__ Ws, const float* __restrict__ Wn,
    const float* __restrict__ bias, float* __restrict__ hs, float* __restrict__ ht) {
  const float* x   = blockIdx.z ? xt   : xs;
  const float* agg = blockIdx.z ? aggt : aggs;
  float*       h   = blockIdx.z ? ht   : hs;
  int n0 = blockIdx.x * 64, m0 = blockIdx.y * 64;
  int tid = threadIdx.x, tx = tid & 15, ty = tid >> 4;
  __shared__ __align__(16) float sA[16][68];
  __shared__ __align__(16) float sB[16][68];
  float acc[4][4] = {};
  for (int phase = 0; phase < 2; phase++) {
    const float* A  = phase ? agg : x;
    const float* Bw = phase ? Wn  : Ws;
    for (int kb = 0; kb < F_; kb += 16) {
      int row = tid >> 2, k4 = (tid & 3) * 4;
      float4 va = *(const float4*)(A + (size_t)(m0 + row) * F_ + kb + k4);
      sA[k4 + 0][row] = va.x; sA[k4 + 1][row] = va.y;
      sA[k4 + 2][row] = va.z; sA[k4 + 3][row] = va.w;
      int k = tid >> 4, n4 = (tid & 15) * 4;
      *(float4*)&sB[k][n4] = *(const float4*)(Bw + (size_t)(kb + k) * F_ + n0 + n4);
      __syncthreads();
#pragma unroll
      for (int kk = 0; kk < 16; kk++) {
        float a[4], bb[4];
        *(float4*)a  = *(const float4*)&sA[kk][ty * 4];
        *(float4*)bb = *(const float4*)&sB[kk][tx * 4];
#pragma unroll
        for (int i = 0; i < 4; i++)
#pragma unroll
          for (int j = 0; j < 4; j++) acc[i][j] += a[i] * bb[j];
      }
      __syncthreads();
    }
  }
  float4 bv = *(const float4*)(bias + n0 + tx * 4);
  float bj[4] = {bv.x, bv.y, bv.z, bv.w};
#pragma unroll
  for (int i = 0; i < 4; i++) {
    int m = m0 + ty * 4 + i;
    float4 o;
    o.x = fmaxf(acc[i][0] + bj[0], 0.f); o.y = fmaxf(acc[i][1] + bj[1], 0.f);
    o.z = fmaxf(acc[i][2] + bj[2], 0.f); o.w = fmaxf(acc[i][3] + bj[3], 0.f);
    *(float4*)(h + (size_t)m * F_ + n0 + tx * 4) = o;
  }
}

// ---------- S_hat[b] = h_s[b] @ h_t[b]^T  (NT), 128x128 tile, 8x8 micro ----------
__global__ __launch_bounds__(256) void shat_gemm(
    const float* __restrict__ hs, const float* __restrict__ ht, float* __restrict__ S) {
  int b = blockIdx.z;
  int n0 = blockIdx.x * 128, m0 = blockIdx.y * 128;
  int tid = threadIdx.x, tx = tid & 15, ty = tid >> 4;
  __shared__ __align__(16) float sA[16][132];
  __shared__ __align__(16) float sB[16][132];
  float acc[8][8] = {};
  const float* Ag = hs + (size_t)(b * N_ + m0) * F_;
  const float* Bg = ht + (size_t)(b * N_ + n0) * F_;
  for (int kb = 0; kb < F_; kb += 16) {
#pragma unroll
    for (int l = 0; l < 2; l++) {
      int idx = tid + l * 256;
      int row = idx >> 2, k4 = (idx & 3) * 4;
      float4 va = *(const float4*)(Ag + (size_t)row * F_ + kb + k4);
      sA[k4 + 0][row] = va.x; sA[k4 + 1][row] = va.y;
      sA[k4 + 2][row] = va.z; sA[k4 + 3][row] = va.w;
      float4 vb = *(const float4*)(Bg + (size_t)row * F_ + kb + k4);
      sB[k4 + 0][row] = vb.x; sB[k4 + 1][row] = vb.y;
      sB[k4 + 2][row] = vb.z; sB[k4 + 3][row] = vb.w;
    }
    __syncthreads();
#pragma unroll
    for (int kk = 0; kk < 16; kk++) {
      float a[8], bb[8];
      *(float4*)&a[0]  = *(const float4*)&sA[kk][ty * 8];
      *(float4*)&a[4]  = *(const float4*)&sA[kk][ty * 8 + 4];
      *(float4*)&bb[0] = *(const float4*)&sB[kk][tx * 8];
      *(float4*)&bb[4] = *(const float4*)&sB[kk][tx * 8 + 4];
#pragma unroll
      for (int i = 0; i < 8; i++)
#pragma unroll
        for (int j = 0; j < 8; j++) acc[i][j] += a[i] * bb[j];
    }
    __syncthreads();
  }
#pragma unroll
  for (int i = 0; i < 8; i++) {
    size_t off = ((size_t)(b * N_ + m0 + ty * 8 + i)) * N_ + n0 + tx * 8;
    float4 o0 = {acc[i][0], acc[i][1], acc[i][2], acc[i][3]};
    float4 o1 = {acc[i][4], acc[i][5], acc[i][6], acc[i][7]};
    *(float4*)(S + off) = o0; *(float4*)(S + off + 4) = o1;
  }
}

// ---------------- row softmax over N=1024, one block per row ----------------
__global__ __launch_bounds__(256) void softmax_row(
    const float* __restrict__ in, float* __restrict__ out) {
  int row = blockIdx.x;
  float4 v = ((const float4*)(in + (size_t)row * N_))[threadIdx.x];
  float m = fmaxf(fmaxf(v.x, v.y), fmaxf(v.z, v.w));
#pragma unroll
  for (int o = 32; o > 0; o >>= 1) m = fmaxf(m, __shfl_down(m, o, 64));
  __shared__ float rmax[4], rsum[4];
  int wave = threadIdx.x >> 6, lane = threadIdx.x & 63;
  if (lane == 0) rmax[wave] = m;
  __syncthreads();
  m = fmaxf(fmaxf(rmax[0], rmax[1]), fmaxf(rmax[2], rmax[3]));
  float e0 = __expf(v.x - m), e1 = __expf(v.y - m);
  float e2 = __expf(v.z - m), e3 = __expf(v.w - m);
  float s = e0 + e1 + e2 + e3;
#pragma unroll
  for (int o = 32; o > 0; o >>= 1) s += __shfl_down(s, o, 64);
  if (lane == 0) rsum[wave] = s;
  __syncthreads();
  s = rsum[0] + rsum[1] + rsum[2] + rsum[3];
  float inv = 1.f / s;
  float4 o4 = {e0 * inv, e1 * inv, e2 * inv, e3 * inv};
  ((float4*)(out + (size_t)row * N_))[threadIdx.x] = o4;
}

// ---- r_t partial: part[b][c][t][r] = sum_{s in chunk c} S[b,s,t]*r_s[b,s,r] ----
// EXP variant reads raw Shat + row stats and applies softmax on the fly.
template <bool EXP>
__global__ __launch_bounds__(256) void rt_part_k(
    const float* __restrict__ S, const float2* __restrict__ stats,
    const float* __restrict__ rs, float* __restrict__ part) {
  int b = blockIdx.z, c = blockIdx.y, t0 = blockIdx.x * 256;
  int tid = threadIdx.x;
  int s0 = c * 32;
  __shared__ float rsh[32][16];
  __shared__ float sstat[64];
  if (tid < 128) {
    int srow = tid >> 2, c4 = (tid & 3) * 4;
    float4 v = *(const float4*)(rs + ((size_t)(b * N_ + s0 + srow)) * R_ + c4);
    rsh[srow][c4] = v.x; rsh[srow][c4 + 1] = v.y;
    rsh[srow][c4 + 2] = v.z; rsh[srow][c4 + 3] = v.w;
  } else if (EXP && tid < 192) {
    sstat[tid - 128] = ((const float*)(stats + b * N_ + s0))[tid - 128];
  }
  __syncthreads();
  float acc[16] = {};
  const float* Sp = S + ((size_t)(b * N_ + s0)) * N_ + t0 + tid;
#pragma unroll
  for (int s = 0; s < 32; s++) {
    float sv = Sp[(size_t)s * N_];
    if (EXP) sv = __expf(sv - sstat[2 * s]) * sstat[2 * s + 1];
#pragma unroll
    for (int r = 0; r < 16; r++) acc[r] += sv * rsh[s][r];
  }
  float* o = part + ((size_t)((b * 32 + c) * N_) + t0 + tid) * R_;
  *(float4*)(o + 0)  = *(float4*)&acc[0];
  *(float4*)(o + 4)  = *(float4*)&acc[4];
  *(float4*)(o + 8)  = *(float4*)&acc[8];
  *(float4*)(o + 12) = *(float4*)&acc[12];
}

// ---- r_t reduce over 32 chunks ----
__global__ __launch_bounds__(256) void rt_reduce(
    const float* __restrict__ part, float* __restrict__ rt) {
  int gid = blockIdx.x * 256 + threadIdx.x;   // 16384 float4 outputs
  int b = gid >> 12, tr = gid & 4095;
  const float* p = part + (size_t)b * (32 * N_ * R_) + (size_t)tr * 4;
  float4 acc = {0.f, 0.f, 0.f, 0.f};
#pragma unroll
  for (int c = 0; c < 32; c++) {
    float4 v = *(const float4*)(p + (size_t)c * (N_ * R_));
    acc.x += v.x; acc.y += v.y; acc.z += v.z; acc.w += v.w;
  }
  ((float4*)rt)[gid] = acc;
}

// ---- fused gather + psi2 + @Wm1: P = relu(v@W2s + (gather v)@W2n + b2) @ Wm1 ----
__global__ __launch_bounds__(256) void gpsi2p(
    const float* __restrict__ vs, const float* __restrict__ vt,
    const int* __restrict__ csr, const int* __restrict__ offs,
    const float* __restrict__ W2s, const float* __restrict__ W2n,
    const float* __restrict__ b2, const float* __restrict__ Wm1,
    float* __restrict__ Ps, float* __restrict__ Pt) {
  const float* v = blockIdx.y ? vt : vs;
  const int* cs = csr + blockIdx.y * E_;
  const int* of = offs + blockIdx.y * (BN_ + 1);
  float* P = blockIdx.y ? Pt : Ps;
  int col = threadIdx.x & 15, row = threadIdx.x >> 4;
  int node = blockIdx.x * 16 + row;
  int j0 = of[node], j1 = of[node + 1];
  float a0 = 0.f, a1 = 0.f, a2 = 0.f, a3 = 0.f;
  int j = j0;
  for (; j + 3 < j1; j += 4) {
    int s0 = cs[j], s1 = cs[j + 1], s2 = cs[j + 2], s3 = cs[j + 3];
    a0 += v[(size_t)s0 * R_ + col];
    a1 += v[(size_t)s1 * R_ + col];
    a2 += v[(size_t)s2 * R_ + col];
    a3 += v[(size_t)s3 * R_ + col];
  }
  for (; j < j1; j++) a0 += v[(size_t)cs[j] * R_ + col];
  __shared__ float sWs[16][16], sWn[16][16], sWm[16][17];
  __shared__ float sv[16][17], sa[16][17], so[16][17];
  sWs[row][col] = W2s[row * 16 + col];
  sWn[row][col] = W2n[row * 16 + col];
  sWm[row][col] = Wm1[row * 16 + col];
  sv[row][col] = v[(size_t)node * R_ + col];
  sa[row][col] = (a0 + a1) + (a2 + a3);
  __syncthreads();
  float o = b2[col];
#pragma unroll
  for (int k = 0; k < 16; k++) o += sv[row][k] * sWs[k][col] + sa[row][k] * sWn[k][col];
  so[row][col] = fmaxf(o, 0.f);
  __syncthreads();
  float p = 0;
#pragma unroll
  for (int k = 0; k < 16; k++) p += so[row][k] * sWm[k][col];
  P[(size_t)node * R_ + col] = p;
}

// ---- full-row update, ONE s-row per block (4096 blocks): latency-friendly shape ----
// Shat[b,s,t] += sum_r relu(Ps[s,r]-Pt[t,r]+bm1[r])*Wm2[r] + bm2, then row softmax info.
// LAST=0: write updated Shat + row stats (max, 1/sumexp).
// LAST=1: don't write Shat; write SL = softmax(updated row) directly.
template <int LAST>
__global__ __launch_bounds__(256) void upd_row2(
    float* __restrict__ Shat, const float* __restrict__ Ps, const float* __restrict__ Pt,
    const float* __restrict__ bm1, const float* __restrict__ Wm2,
    const float* __restrict__ bm2, float2* __restrict__ stats, float* __restrict__ SL) {
  int b = blockIdx.y, s = blockIdx.x;
  int tid = threadIdx.x;
  __shared__ __align__(16) float pt[256][17];
  __shared__ float sps[16], sb[16], sw[16];
  __shared__ float wred[4];
  if (tid < 16) {
    sps[tid] = Ps[((size_t)(b * N_ + s)) * R_ + tid];
    sb[tid] = bm1[tid];
    sw[tid] = Wm2[tid];
  }
  float bm2v = bm2[0];
  const size_t rowoff = (size_t)(b * N_ + s) * N_;
  float vals[4];
  for (int tile = 0; tile < 4; tile++) {
    int t0 = tile * 256;
    __syncthreads();
    for (int i = tid; i < 1024; i += 256) {
      int tr = i >> 2, c = (i & 3) * 4;
      float4 v = *(const float4*)(Pt + ((size_t)(b * N_ + t0 + tr)) * R_ + c);
      pt[tr][c] = v.x; pt[tr][c + 1] = v.y; pt[tr][c + 2] = v.z; pt[tr][c + 3] = v.w;
    }
    __syncthreads();
    float sum = bm2v;
#pragma unroll
    for (int r = 0; r < 16; r++) sum += fmaxf(sps[r] - pt[tid][r] + sb[r], 0.f) * sw[r];
    float vv = Shat[rowoff + t0 + tid] + sum;
    vals[tile] = vv;
    if (!LAST) Shat[rowoff + t0 + tid] = vv;
  }
  // --- row max ---
  int wave = tid >> 6, lane = tid & 63;
  float m = fmaxf(fmaxf(vals[0], vals[1]), fmaxf(vals[2], vals[3]));
#pragma unroll
  for (int o = 32; o > 0; o >>= 1) m = fmaxf(m, __shfl_down(m, o, 64));
  if (lane == 0) wred[wave] = m;
  __syncthreads();
  m = fmaxf(fmaxf(wred[0], wred[1]), fmaxf(wred[2], wred[3]));
  __syncthreads();
  // --- row expsum ---
  float e0 = __expf(vals[0] - m), e1 = __expf(vals[1] - m);
  float e2 = __expf(vals[2] - m), e3 = __expf(vals[3] - m);
  float l = (e0 + e1) + (e2 + e3);
#pragma unroll
  for (int o = 32; o > 0; o >>= 1) l += __shfl_down(l, o, 64);
  if (lane == 0) wred[wave] = l;
  __syncthreads();
  l = (wred[0] + wred[1]) + (wred[2] + wred[3]);
  if (LAST) {
    float inv = 1.f / l;
    SL[rowoff + 0 * 256 + tid] = e0 * inv;
    SL[rowoff + 1 * 256 + tid] = e1 * inv;
    SL[rowoff + 2 * 256 + tid] = e2 * inv;
    SL[rowoff + 3 * 256 + tid] = e3 * inv;
  } else {
    if (tid == 0) stats[b * N_ + s] = make_float2(m, 1.f / l);
  }
}

extern "C" void kernel_launch(void* const* d_in, const int* in_sizes, int n_in,
                              void* d_out, int out_size, void* d_ws, size_t ws_size,
                              hipStream_t stream) {
  const float* x_s = (const float*)d_in[0];
  const int*   ei_s = (const int*)d_in[1];
  const float* x_t = (const float*)d_in[2];
  const int*   ei_t = (const int*)d_in[3];
  const float* W1s = (const float*)d_in[4];
  const float* W1n = (const float*)d_in[5];
  const float* b1  = (const float*)d_in[6];
  const float* W2s = (const float*)d_in[7];
  const float* W2n = (const float*)d_in[8];
  const float* b2  = (const float*)d_in[9];
  const float* Wm1 = (const float*)d_in[10];
  const float* bm1 = (const float*)d_in[11];
  const float* Wm2 = (const float*)d_in[12];
  const float* bm2 = (const float*)d_in[13];
  const float* r_steps = (const float*)d_in[14];

  float* out = (float*)d_out;
  float* S0 = out;                         // [4,1024,1024]
  float* SL = out + (size_t)B_ * N_ * N_;  // [4,1024,1024]

  float* ws = (float*)d_ws;
  float* agg_s = ws;                       // 524288   (dead after psi1_gemm)
  float* agg_t = ws + 524288;              // 524288   (dead after psi1_gemm)
  float* h_s   = ws + 1048576;             // 524288   (dead after shat_gemm)
  float* h_t   = ws + 1572864;             // 524288   (dead after shat_gemm)
  float* part  = ws;                       // 2097152 floats = 8MB, reuses agg+h region
  float* Shat  = ws + 2097152;             // 4194304
  float* rtb   = ws + 6291456;             // 65536
  float2* stats = (float2*)(ws + 6356992); // 8192 floats (4096 float2)
  float* Ps    = ws + 6488064;             // 65536
  float* Pt    = ws + 6553600;             // 65536
  int* counts  = (int*)(ws + 6619136);     // 8192
  int* cursor  = (int*)(ws + 6627328);     // 8192
  int* offs    = (int*)(ws + 6635520);     // 8194 (2 x 4097)
  int* csr     = (int*)(ws + 6643720);     // 131072

  // ---- CSR build: parallel 4-dispatch chain ----
  hipMemsetAsync(counts, 0, 2 * BN_ * sizeof(int), stream);
  hist_k<<<dim3(E_ / 256, 2), 256, 0, stream>>>(ei_s, ei_t, counts);
  csr_scan<<<2, 256, 0, stream>>>(counts, offs, cursor);
  csr_fill<<<dim3(E_ / 256, 2), 256, 0, stream>>>(ei_s, ei_t, cursor, csr);

  // ---- psi1 on both graphs ----
  gather_f<<<dim3(BN_ / 2, 2), 256, 0, stream>>>(x_s, x_t, csr, offs, agg_s, agg_t);
  psi1_gemm<<<dim3(2, 64, 2), 256, 0, stream>>>(x_s, agg_s, x_t, agg_t, W1s, W1n, b1, h_s, h_t);

  // ---- S_hat and S_0 ----
  shat_gemm<<<dim3(8, 8, 4), 256, 0, stream>>>(h_s, h_t, Shat);
  softmax_row<<<B_ * N_, 256, 0, stream>>>(Shat, S0);

  // ---- step 0 ----
  const float* rs0 = r_steps;
  rt_part_k<false><<<dim3(4, 32, 4), 256, 0, stream>>>(S0, nullptr, rs0, part);
  rt_reduce<<<64, 256, 0, stream>>>(part, rtb);
  gpsi2p<<<dim3(256, 2), 256, 0, stream>>>(rs0, rtb, csr, offs, W2s, W2n, b2, Wm1, Ps, Pt);
  upd_row2<0><<<dim3(N_, B_), 256, 0, stream>>>(Shat, Ps, Pt, bm1, Wm2, bm2, stats, nullptr);

  // ---- step 1 (softmax fused into rt_part via stats; S_L written by upd_row2) ----
  const float* rs1 = r_steps + (size_t)B_ * N_ * R_;
  rt_part_k<true><<<dim3(4, 32, 4), 256, 0, stream>>>(Shat, stats, rs1, part);
  rt_reduce<<<64, 256, 0, stream>>>(part, rtb);
  gpsi2p<<<dim3(256, 2), 256, 0, stream>>>(rs1, rtb, csr, offs, W2s, W2n, b2, Wm1, Ps, Pt);
  upd_row2<1><<<dim3(N_, B_), 256, 0, stream>>>(Shat, Ps, Pt, bm1, Wm2, bm2, nullptr, SL);
}

// Round 8
// 230.532 us; speedup vs baseline: 1.4633x; 1.1137x over previous
//
#include <hip/hip_runtime.h>

#define B_ 4
#define N_ 1024
#define F_ 128
#define R_ 16
#define E_ 65536
#define BN_ 4096

// ---------------- CSR build: histogram of dst (parallel, global atomics) ----------------
__global__ __launch_bounds__(256) void hist_k(
    const int* __restrict__ eis, const int* __restrict__ eit, int* __restrict__ counts) {
  const int* ei = blockIdx.y ? eit : eis;
  int* c = counts + blockIdx.y * BN_;
  int e = blockIdx.x * 256 + threadIdx.x;
  atomicAdd(c + ei[E_ + e], 1);
}

// ---------------- CSR build: exclusive scan (4096 = 256 threads x 16) ----------------
__global__ __launch_bounds__(256) void csr_scan(
    const int* __restrict__ counts, int* __restrict__ offs, int* __restrict__ cursor) {
  const int* c = counts + blockIdx.x * BN_;
  int* o = offs + blockIdx.x * (BN_ + 1);
  int* cur = cursor + blockIdx.x * BN_;
  int tid = threadIdx.x;
  int base = tid * 16;
  int local[16], sum = 0;
#pragma unroll
  for (int i = 0; i < 16; i++) { local[i] = sum; sum += c[base + i]; }
  __shared__ int csum[256];
  csum[tid] = sum;
  __syncthreads();
  for (int d = 1; d < 256; d <<= 1) {
    int v = (tid >= d) ? csum[tid - d] : 0;
    __syncthreads();
    csum[tid] += v;
    __syncthreads();
  }
  int prev = (tid == 0) ? 0 : csum[tid - 1];
#pragma unroll
  for (int i = 0; i < 16; i++) { int off = prev + local[i]; o[base + i] = off; cur[base + i] = off; }
  if (tid == 255) o[BN_] = csum[255];
}

// ---------------- CSR build: fill src lists ----------------
__global__ __launch_bounds__(256) void csr_fill(
    const int* __restrict__ eis, const int* __restrict__ eit,
    int* __restrict__ cursor, int* __restrict__ csr) {
  const int* ei = blockIdx.y ? eit : eis;
  int* cur = cursor + blockIdx.y * BN_;
  int* cs = csr + blockIdx.y * E_;
  int e = blockIdx.x * 256 + threadIdx.x;
  int src = ei[e], dst = ei[E_ + e];
  int pos = atomicAdd(cur + dst, 1);
  cs[pos] = src;
}

// ---------------- psi1 aggregation via gather, 4-way ILP ----------------
__global__ __launch_bounds__(256) void gather_f(
    const float* __restrict__ xs, const float* __restrict__ xt,
    const int* __restrict__ csr, const int* __restrict__ offs,
    float* __restrict__ aggs, float* __restrict__ aggt) {
  const float* x = blockIdx.y ? xt : xs;
  const int* cs = csr + blockIdx.y * E_;
  const int* of = offs + blockIdx.y * (BN_ + 1);
  float* agg = blockIdx.y ? aggt : aggs;
  int node = blockIdx.x * 2 + (threadIdx.x >> 7);
  int ch = threadIdx.x & 127;
  int j0 = of[node], j1 = of[node + 1];
  float a0 = 0.f, a1 = 0.f, a2 = 0.f, a3 = 0.f;
  int j = j0;
  for (; j + 3 < j1; j += 4) {
    int s0 = cs[j], s1 = cs[j + 1], s2 = cs[j + 2], s3 = cs[j + 3];
    a0 += x[(size_t)s0 * F_ + ch];
    a1 += x[(size_t)s1 * F_ + ch];
    a2 += x[(size_t)s2 * F_ + ch];
    a3 += x[(size_t)s3 * F_ + ch];
  }
  for (; j < j1; j++) a0 += x[(size_t)cs[j] * F_ + ch];
  agg[(size_t)node * F_ + ch] = (a0 + a1) + (a2 + a3);
}

// ------------- h = relu(x@Ws + agg@Wn + b), M=4096 N=128 K=128x2 -------------
__global__ __launch_bounds__(256) void psi1_gemm(
    const float* __restrict__ xs, const float* __restrict__ aggs,
    const float* __restrict__ xt, const float* __restrict__ aggt,
    const float* __restrict__ Ws, const float* __restrict__ Wn,
    const float* __restrict__ bias, float* __restrict__ hs, float* __restrict__ ht) {
  const float* x   = blockIdx.z ? xt   : xs;
  const float* agg = blockIdx.z ? aggt : aggs;
  float*       h   = blockIdx.z ? ht   : hs;
  int n0 = blockIdx.x * 64, m0 = blockIdx.y * 64;
  int tid = threadIdx.x, tx = tid & 15, ty = tid >> 4;
  __shared__ __align__(16) float sA[16][68];
  __shared__ __align__(16) float sB[16][68];
  float acc[4][4] = {};
  for (int phase = 0; phase < 2; phase++) {
    const float* A  = phase ? agg : x;
    const float* Bw = phase ? Wn  : Ws;
    for (int kb = 0; kb < F_; kb += 16) {
      int row = tid >> 2, k4 = (tid & 3) * 4;
      float4 va = *(const float4*)(A + (size_t)(m0 + row) * F_ + kb + k4);
      sA[k4 + 0][row] = va.x; sA[k4 + 1][row] = va.y;
      sA[k4 + 2][row] = va.z; sA[k4 + 3][row] = va.w;
      int k = tid >> 4, n4 = (tid & 15) * 4;
      *(float4*)&sB[k][n4] = *(const float4*)(Bw + (size_t)(kb + k) * F_ + n0 + n4);
      __syncthreads();
#pragma unroll
      for (int kk = 0; kk < 16; kk++) {
        float a[4], bb[4];
        *(float4*)a  = *(const float4*)&sA[kk][ty * 4];
        *(float4*)bb = *(const float4*)&sB[kk][tx * 4];
#pragma unroll
        for (int i = 0; i < 4; i++)
#pragma unroll
          for (int j = 0; j < 4; j++) acc[i][j] += a[i] * bb[j];
      }
      __syncthreads();
    }
  }
  float4 bv = *(const float4*)(bias + n0 + tx * 4);
  float bj[4] = {bv.x, bv.y, bv.z, bv.w};
#pragma unroll
  for (int i = 0; i < 4; i++) {
    int m = m0 + ty * 4 + i;
    float4 o;
    o.x = fmaxf(acc[i][0] + bj[0], 0.f); o.y = fmaxf(acc[i][1] + bj[1], 0.f);
    o.z = fmaxf(acc[i][2] + bj[2], 0.f); o.w = fmaxf(acc[i][3] + bj[3], 0.f);
    *(float4*)(h + (size_t)m * F_ + n0 + tx * 4) = o;
  }
}

// ---------- S_hat[b] = h_s[b] @ h_t[b]^T  (NT), 128x128 tile, 8x8 micro ----------
__global__ __launch_bounds__(256) void shat_gemm(
    const float* __restrict__ hs, const float* __restrict__ ht, float* __restrict__ S) {
  int b = blockIdx.z;
  int n0 = blockIdx.x * 128, m0 = blockIdx.y * 128;
  int tid = threadIdx.x, tx = tid & 15, ty = tid >> 4;
  __shared__ __align__(16) float sA[16][132];
  __shared__ __align__(16) float sB[16][132];
  float acc[8][8] = {};
  const float* Ag = hs + (size_t)(b * N_ + m0) * F_;
  const float* Bg = ht + (size_t)(b * N_ + n0) * F_;
  for (int kb = 0; kb < F_; kb += 16) {
#pragma unroll
    for (int l = 0; l < 2; l++) {
      int idx = tid + l * 256;
      int row = idx >> 2, k4 = (idx & 3) * 4;
      float4 va = *(const float4*)(Ag + (size_t)row * F_ + kb + k4);
      sA[k4 + 0][row] = va.x; sA[k4 + 1][row] = va.y;
      sA[k4 + 2][row] = va.z; sA[k4 + 3][row] = va.w;
      float4 vb = *(const float4*)(Bg + (size_t)row * F_ + kb + k4);
      sB[k4 + 0][row] = vb.x; sB[k4 + 1][row] = vb.y;
      sB[k4 + 2][row] = vb.z; sB[k4 + 3][row] = vb.w;
    }
    __syncthreads();
#pragma unroll
    for (int kk = 0; kk < 16; kk++) {
      float a[8], bb[8];
      *(float4*)&a[0]  = *(const float4*)&sA[kk][ty * 8];
      *(float4*)&a[4]  = *(const float4*)&sA[kk][ty * 8 + 4];
      *(float4*)&bb[0] = *(const float4*)&sB[kk][tx * 8];
      *(float4*)&bb[4] = *(const float4*)&sB[kk][tx * 8 + 4];
#pragma unroll
      for (int i = 0; i < 8; i++)
#pragma unroll
        for (int j = 0; j < 8; j++) acc[i][j] += a[i] * bb[j];
    }
    __syncthreads();
  }
#pragma unroll
  for (int i = 0; i < 8; i++) {
    size_t off = ((size_t)(b * N_ + m0 + ty * 8 + i)) * N_ + n0 + tx * 8;
    float4 o0 = {acc[i][0], acc[i][1], acc[i][2], acc[i][3]};
    float4 o1 = {acc[i][4], acc[i][5], acc[i][6], acc[i][7]};
    *(float4*)(S + off) = o0; *(float4*)(S + off + 4) = o1;
  }
}

// ---------------- row softmax over N=1024, one block per row ----------------
__global__ __launch_bounds__(256) void softmax_row(
    const float* __restrict__ in, float* __restrict__ out) {
  int row = blockIdx.x;
  float4 v = ((const float4*)(in + (size_t)row * N_))[threadIdx.x];
  float m = fmaxf(fmaxf(v.x, v.y), fmaxf(v.z, v.w));
#pragma unroll
  for (int o = 32; o > 0; o >>= 1) m = fmaxf(m, __shfl_down(m, o, 64));
  __shared__ float rmax[4], rsum[4];
  int wave = threadIdx.x >> 6, lane = threadIdx.x & 63;
  if (lane == 0) rmax[wave] = m;
  __syncthreads();
  m = fmaxf(fmaxf(rmax[0], rmax[1]), fmaxf(rmax[2], rmax[3]));
  float e0 = __expf(v.x - m), e1 = __expf(v.y - m);
  float e2 = __expf(v.z - m), e3 = __expf(v.w - m);
  float s = e0 + e1 + e2 + e3;
#pragma unroll
  for (int o = 32; o > 0; o >>= 1) s += __shfl_down(s, o, 64);
  if (lane == 0) rsum[wave] = s;
  __syncthreads();
  s = rsum[0] + rsum[1] + rsum[2] + rsum[3];
  float inv = 1.f / s;
  float4 o4 = {e0 * inv, e1 * inv, e2 * inv, e3 * inv};
  ((float4*)(out + (size_t)row * N_))[threadIdx.x] = o4;
}

// ---- r_t partial: part[b][c][t][r] = sum_{s in chunk c} S[b,s,t]*r_s[b,s,r] ----
// EXP variant reads raw Shat + row stats and applies softmax on the fly.
template <bool EXP>
__global__ __launch_bounds__(256) void rt_part_k(
    const float* __restrict__ S, const float2* __restrict__ stats,
    const float* __restrict__ rs, float* __restrict__ part) {
  int b = blockIdx.z, c = blockIdx.y, t0 = blockIdx.x * 256;
  int tid = threadIdx.x;
  int s0 = c * 32;
  __shared__ float rsh[32][16];
  __shared__ float sstat[64];
  if (tid < 128) {
    int srow = tid >> 2, c4 = (tid & 3) * 4;
    float4 v = *(const float4*)(rs + ((size_t)(b * N_ + s0 + srow)) * R_ + c4);
    rsh[srow][c4] = v.x; rsh[srow][c4 + 1] = v.y;
    rsh[srow][c4 + 2] = v.z; rsh[srow][c4 + 3] = v.w;
  } else if (EXP && tid < 192) {
    sstat[tid - 128] = ((const float*)(stats + b * N_ + s0))[tid - 128];
  }
  __syncthreads();
  float acc[16] = {};
  const float* Sp = S + ((size_t)(b * N_ + s0)) * N_ + t0 + tid;
#pragma unroll
  for (int s = 0; s < 32; s++) {
    float sv = Sp[(size_t)s * N_];
    if (EXP) sv = __expf(sv - sstat[2 * s]) * sstat[2 * s + 1];
#pragma unroll
    for (int r = 0; r < 16; r++) acc[r] += sv * rsh[s][r];
  }
  float* o = part + ((size_t)((b * 32 + c) * N_) + t0 + tid) * R_;
  *(float4*)(o + 0)  = *(float4*)&acc[0];
  *(float4*)(o + 4)  = *(float4*)&acc[4];
  *(float4*)(o + 8)  = *(float4*)&acc[8];
  *(float4*)(o + 12) = *(float4*)&acc[12];
}

// ---- r_t reduce over 32 chunks ----
__global__ __launch_bounds__(256) void rt_reduce(
    const float* __restrict__ part, float* __restrict__ rt) {
  int gid = blockIdx.x * 256 + threadIdx.x;   // 16384 float4 outputs
  int b = gid >> 12, tr = gid & 4095;
  const float* p = part + (size_t)b * (32 * N_ * R_) + (size_t)tr * 4;
  float4 acc = {0.f, 0.f, 0.f, 0.f};
#pragma unroll
  for (int c = 0; c < 32; c++) {
    float4 v = *(const float4*)(p + (size_t)c * (N_ * R_));
    acc.x += v.x; acc.y += v.y; acc.z += v.z; acc.w += v.w;
  }
  ((float4*)rt)[gid] = acc;
}

// ---- fused gather + psi2 + @Wm1: P = relu(v@W2s + (gather v)@W2n + b2) @ Wm1 ----
// Source side writes Ps row-major [BN][16]; target side writes Pt4 [4][BN][4]
// (transposed-by-4 layout so upd_row3 reads its 16 values as 4 coalesced float4s).
__global__ __launch_bounds__(256) void gpsi2p(
    const float* __restrict__ vs, const float* __restrict__ vt,
    const int* __restrict__ csr, const int* __restrict__ offs,
    const float* __restrict__ W2s, const float* __restrict__ W2n,
    const float* __restrict__ b2, const float* __restrict__ Wm1,
    float* __restrict__ Ps, float* __restrict__ Pt4) {
  const float* v = blockIdx.y ? vt : vs;
  const int* cs = csr + blockIdx.y * E_;
  const int* of = offs + blockIdx.y * (BN_ + 1);
  int col = threadIdx.x & 15, row = threadIdx.x >> 4;
  int node = blockIdx.x * 16 + row;
  int j0 = of[node], j1 = of[node + 1];
  float a0 = 0.f, a1 = 0.f, a2 = 0.f, a3 = 0.f;
  int j = j0;
  for (; j + 3 < j1; j += 4) {
    int s0 = cs[j], s1 = cs[j + 1], s2 = cs[j + 2], s3 = cs[j + 3];
    a0 += v[(size_t)s0 * R_ + col];
    a1 += v[(size_t)s1 * R_ + col];
    a2 += v[(size_t)s2 * R_ + col];
    a3 += v[(size_t)s3 * R_ + col];
  }
  for (; j < j1; j++) a0 += v[(size_t)cs[j] * R_ + col];
  __shared__ float sWs[16][16], sWn[16][16], sWm[16][17];
  __shared__ float sv[16][17], sa[16][17], so[16][17];
  sWs[row][col] = W2s[row * 16 + col];
  sWn[row][col] = W2n[row * 16 + col];
  sWm[row][col] = Wm1[row * 16 + col];
  sv[row][col] = v[(size_t)node * R_ + col];
  sa[row][col] = (a0 + a1) + (a2 + a3);
  __syncthreads();
  float o = b2[col];
#pragma unroll
  for (int k = 0; k < 16; k++) o += sv[row][k] * sWs[k][col] + sa[row][k] * sWn[k][col];
  so[row][col] = fmaxf(o, 0.f);
  __syncthreads();
  float p = 0;
#pragma unroll
  for (int k = 0; k < 16; k++) p += so[row][k] * sWm[k][col];
  if (blockIdx.y) {
    Pt4[((size_t)(col >> 2) * BN_ + node) * 4 + (col & 3)] = p;
  } else {
    Ps[(size_t)node * R_ + col] = p;
  }
}

// ---- full-row update, one s-row per block, NO LDS staging, no mid-kernel barriers ----
// Pt in [4][BN][4] layout: thread reads its own t's 16 values via 4 coalesced float4s.
// LAST=0: write updated Shat + row stats (max, 1/sumexp).
// LAST=1: don't write Shat; write SL = softmax(updated row) directly.
template <int LAST>
__global__ __launch_bounds__(256) void upd_row3(
    float* __restrict__ Shat, const float* __restrict__ Ps, const float* __restrict__ Pt4,
    const float* __restrict__ bm1, const float* __restrict__ Wm2,
    const float* __restrict__ bm2, float2* __restrict__ stats, float* __restrict__ SL) {
  int b = blockIdx.y, s = blockIdx.x;
  int tid = threadIdx.x;
  __shared__ float sc[16], sw[16];   // sc[r] = Ps[s][r] + bm1[r]
  __shared__ float wred[4];
  if (tid < 16) {
    sc[tid] = Ps[((size_t)(b * N_ + s)) * R_ + tid] + bm1[tid];
    sw[tid] = Wm2[tid];
  }
  float bm2v = bm2[0];
  __syncthreads();
  const size_t rowoff = (size_t)(b * N_ + s) * N_;
  float vals[4];
#pragma unroll
  for (int tile = 0; tile < 4; tile++) {
    int gt = b * N_ + tile * 256 + tid;   // global t-node id
    float pt[16];
    *(float4*)&pt[0]  = *(const float4*)(Pt4 + ((size_t)0 * BN_ + gt) * 4);
    *(float4*)&pt[4]  = *(const float4*)(Pt4 + ((size_t)1 * BN_ + gt) * 4);
    *(float4*)&pt[8]  = *(const float4*)(Pt4 + ((size_t)2 * BN_ + gt) * 4);
    *(float4*)&pt[12] = *(const float4*)(Pt4 + ((size_t)3 * BN_ + gt) * 4);
    float sh = Shat[rowoff + tile * 256 + tid];
    float sum = bm2v;
#pragma unroll
    for (int r = 0; r < 16; r++) sum += fmaxf(sc[r] - pt[r], 0.f) * sw[r];
    float vv = sh + sum;
    vals[tile] = vv;
    if (!LAST) Shat[rowoff + tile * 256 + tid] = vv;
  }
  // --- row max ---
  int wave = tid >> 6, lane = tid & 63;
  float m = fmaxf(fmaxf(vals[0], vals[1]), fmaxf(vals[2], vals[3]));
#pragma unroll
  for (int o = 32; o > 0; o >>= 1) m = fmaxf(m, __shfl_down(m, o, 64));
  if (lane == 0) wred[wave] = m;
  __syncthreads();
  m = fmaxf(fmaxf(wred[0], wred[1]), fmaxf(wred[2], wred[3]));
  __syncthreads();
  // --- row expsum ---
  float e0 = __expf(vals[0] - m), e1 = __expf(vals[1] - m);
  float e2 = __expf(vals[2] - m), e3 = __expf(vals[3] - m);
  float l = (e0 + e1) + (e2 + e3);
#pragma unroll
  for (int o = 32; o > 0; o >>= 1) l += __shfl_down(l, o, 64);
  if (lane == 0) wred[wave] = l;
  __syncthreads();
  l = (wred[0] + wred[1]) + (wred[2] + wred[3]);
  if (LAST) {
    float inv = 1.f / l;
    SL[rowoff + 0 * 256 + tid] = e0 * inv;
    SL[rowoff + 1 * 256 + tid] = e1 * inv;
    SL[rowoff + 2 * 256 + tid] = e2 * inv;
    SL[rowoff + 3 * 256 + tid] = e3 * inv;
  } else {
    if (tid == 0) stats[b * N_ + s] = make_float2(m, 1.f / l);
  }
}

extern "C" void kernel_launch(void* const* d_in, const int* in_sizes, int n_in,
                              void* d_out, int out_size, void* d_ws, size_t ws_size,
                              hipStream_t stream) {
  const float* x_s = (const float*)d_in[0];
  const int*   ei_s = (const int*)d_in[1];
  const float* x_t = (const float*)d_in[2];
  const int*   ei_t = (const int*)d_in[3];
  const float* W1s = (const float*)d_in[4];
  const float* W1n = (const float*)d_in[5];
  const float* b1  = (const float*)d_in[6];
  const float* W2s = (const float*)d_in[7];
  const float* W2n = (const float*)d_in[8];
  const float* b2  = (const float*)d_in[9];
  const float* Wm1 = (const float*)d_in[10];
  const float* bm1 = (const float*)d_in[11];
  const float* Wm2 = (const float*)d_in[12];
  const float* bm2 = (const float*)d_in[13];
  const float* r_steps = (const float*)d_in[14];

  float* out = (float*)d_out;
  float* S0 = out;                         // [4,1024,1024]
  float* SL = out + (size_t)B_ * N_ * N_;  // [4,1024,1024]

  float* ws = (float*)d_ws;
  float* agg_s = ws;                       // 524288   (dead after psi1_gemm)
  float* agg_t = ws + 524288;              // 524288   (dead after psi1_gemm)
  float* h_s   = ws + 1048576;             // 524288   (dead after shat_gemm)
  float* h_t   = ws + 1572864;             // 524288   (dead after shat_gemm)
  float* part  = ws;                       // 2097152 floats = 8MB, reuses agg+h region
  float* Shat  = ws + 2097152;             // 4194304
  float* rtb   = ws + 6291456;             // 65536
  float2* stats = (float2*)(ws + 6356992); // 8192 floats (4096 float2)
  float* Ps    = ws + 6488064;             // 65536
  float* Pt4   = ws + 6553600;             // 65536 (layout [4][4096][4])
  int* counts  = (int*)(ws + 6619136);     // 8192
  int* cursor  = (int*)(ws + 6627328);     // 8192
  int* offs    = (int*)(ws + 6635520);     // 8194 (2 x 4097)
  int* csr     = (int*)(ws + 6643720);     // 131072

  // ---- CSR build: parallel 4-dispatch chain ----
  hipMemsetAsync(counts, 0, 2 * BN_ * sizeof(int), stream);
  hist_k<<<dim3(E_ / 256, 2), 256, 0, stream>>>(ei_s, ei_t, counts);
  csr_scan<<<2, 256, 0, stream>>>(counts, offs, cursor);
  csr_fill<<<dim3(E_ / 256, 2), 256, 0, stream>>>(ei_s, ei_t, cursor, csr);

  // ---- psi1 on both graphs ----
  gather_f<<<dim3(BN_ / 2, 2), 256, 0, stream>>>(x_s, x_t, csr, offs, agg_s, agg_t);
  psi1_gemm<<<dim3(2, 64, 2), 256, 0, stream>>>(x_s, agg_s, x_t, agg_t, W1s, W1n, b1, h_s, h_t);

  // ---- S_hat and S_0 ----
  shat_gemm<<<dim3(8, 8, 4), 256, 0, stream>>>(h_s, h_t, Shat);
  softmax_row<<<B_ * N_, 256, 0, stream>>>(Shat, S0);

  // ---- step 0 ----
  const float* rs0 = r_steps;
  rt_part_k<false><<<dim3(4, 32, 4), 256, 0, stream>>>(S0, nullptr, rs0, part);
  rt_reduce<<<64, 256, 0, stream>>>(part, rtb);
  gpsi2p<<<dim3(256, 2), 256, 0, stream>>>(rs0, rtb, csr, offs, W2s, W2n, b2, Wm1, Ps, Pt4);
  upd_row3<0><<<dim3(N_, B_), 256, 0, stream>>>(Shat, Ps, Pt4, bm1, Wm2, bm2, stats, nullptr);

  // ---- step 1 (softmax fused into rt_part via stats; S_L written by upd_row3) ----
  const float* rs1 = r_steps + (size_t)B_ * N_ * R_;
  rt_part_k<true><<<dim3(4, 32, 4), 256, 0, stream>>>(Shat, stats, rs1, part);
  rt_reduce<<<64, 256, 0, stream>>>(part, rtb);
  gpsi2p<<<dim3(256, 2), 256, 0, stream>>>(rs1, rtb, csr, offs, W2s, W2n, b2, Wm1, Ps, Pt4);
  upd_row3<1><<<dim3(N_, B_), 256, 0, stream>>>(Shat, Ps, Pt4, bm1, Wm2, bm2, nullptr, SL);
}